// Round 8
// baseline (166.995 us; speedup 1.0000x reference)
//
#include <hip/hip_runtime.h>

// LocalizationLoss: B=1048576, N=3, C=7. output (B,3,7) fp32, target (B,3,5) fp32.
// result = (5*(Sx+Sy+2*Swh) + 3*Sce - 0.5*Sbce)/(B*N) + 0.5   (scalar fp32)
//
// R1: per-block partials (77->59us).  R2: wave-private LDS, no barriers: 62us.
// R3: 2-deep dbuf w/ stage-before-compute-of-other-buffer: 62us (the wait
//     before each compute drained the just-issued prefetch).
// R4: register ping-pong: 94us (VGPR=152, spills).
// R5: 32-row shots, 20 waves/CU: 58us.
// R6: stage-AFTER-compute rotation (one compute-phase of slack before each
//     wait) + NT staging: kernel dropped below the 53us poison-fills
//     (total 177->163.7, kernel ~45us). Latency exposure was the limiter.
// R7: deepen to depth-2: 1-wave blocks, 3 rotating wave-private buffers,
//     8 shots x 32 rows per wave. At compute(s), stage(s) was issued two
//     compute phases earlier -> ~2x900cyc slack, steady-state fully hidden.
//     13.8KB LDS/block -> 11 blocks/CU = 11 independent waves/CU.

#define NBLK 4096            // 4096 waves x 8 shots x 32 rows = B
#define SHOTS 8
#define INV_BN (1.0f / 3145728.0f)

__device__ __forceinline__ void gl16(const float4* g, float4* l) {
  // aux=2 -> NT (evict-first): streaming data, don't churn L2
  __builtin_amdgcn_global_load_lds(
      (const __attribute__((address_space(1))) unsigned int*)g,
      (__attribute__((address_space(3))) unsigned int*)l, 16, 0, 2);
}

// Stage 32 rows: o = 32*21 = 168 float4; t = 32*15 = 120 float4.
__device__ __forceinline__ void stage32(const float* __restrict__ gout,
                                        const float* __restrict__ gtgt,
                                        size_t row0, int lane,
                                        float* so, float* st) {
  const float4* go4 = (const float4*)(gout + row0 * 21);
  const float4* gt4 = (const float4*)(gtgt + row0 * 15);
  float4* so4 = (float4*)so;
  float4* st4 = (float4*)st;
  gl16(go4 + lane, so4);
  gl16(go4 + 64 + lane, so4 + 64);
  if (lane < 40) gl16(go4 + 128 + lane, so4 + 128);
  gl16(gt4 + lane, st4);
  if (lane < 56) gl16(gt4 + 64 + lane, st4 + 64);
}

// Row math from LDS; active on lanes 0..31 (row = lane). Strides 21/15 odd
// -> 32 lanes hit 32 distinct banks, conflict-free.
__device__ __forceinline__ float compute_row(const float* so, const float* st,
                                             int lane) {
  const float* o = so + lane * 21;
  const float* t = st + lane * 15;
  float pbce = 1.f, sx = 0.f, sy = 0.f, swh = 0.f, sel = 0.f;
  float Lg[3][3];
  int cls[3];
  #pragma unroll
  for (int n = 0; n < 3; ++n) {
    const float tt = t[n * 5 + 0];
    const bool mk = (tt != 0.f);
    const float m = mk ? 1.f : 0.f;
    const float p = o[n * 7 + 0];
    pbce *= mk ? p : 1.f - p;               // 3 logs -> 1
    const float dx = o[n * 7 + 1] * m - t[n * 5 + 1];
    sx += dx * dx;
    const float dy = o[n * 7 + 2] * m - t[n * 5 + 2];
    sy += dy * dy;
    const float o3 = o[n * 7 + 3], t3 = t[n * 5 + 3];
    swh += t3 + (mk ? (o3 - 2.f * __builtin_sqrtf(o3 * t3)) : 0.f);
    Lg[n][0] = o[n * 7 + 4] * m;
    Lg[n][1] = o[n * 7 + 5] * m;
    Lg[n][2] = o[n * 7 + 6] * m;
    cls[n] = (int)t[n * 5 + 4];
  }
  float prodS = 1.f;
  #pragma unroll
  for (int j = 0; j < 3; ++j) {
    prodS *= __expf(Lg[0][j]) + __expf(Lg[1][j]) + __expf(Lg[2][j]);
    const int idx = cls[j];
    sel += (idx == 0) ? Lg[0][j] : ((idx == 1) ? Lg[1][j] : Lg[2][j]);
  }
  return 5.f * (sx + sy + 2.f * swh) + 3.f * (__logf(prodS) - sel)
         - 0.5f * __logf(pbce);
}

__global__ __launch_bounds__(64, 4) void loc_loss_kernel(
    const float* __restrict__ gout, const float* __restrict__ gtgt,
    float* __restrict__ ws) {
  // 3 rotating buffers: 3*(2688+1920) = 13824 B -> 11 blocks/CU.
  __shared__ float sb_o[3][32 * 21];
  __shared__ float sb_t[3][32 * 15];

  const int lane = threadIdx.x;
  const size_t base = (size_t)blockIdx.x * (SHOTS * 32);

  // Prologue: fill all 3 buffers (15 outstanding staging loads).
  stage32(gout, gtgt, base +  0, lane, sb_o[0], sb_t[0]);
  stage32(gout, gtgt, base + 32, lane, sb_o[1], sb_t[1]);
  stage32(gout, gtgt, base + 64, lane, sb_o[2], sb_t[2]);

  float acc = 0.f;
  #pragma unroll
  for (int s = 0; s < SHOTS; ++s) {
    const int b = s % 3;
    if (lane < 32) acc += compute_row(sb_o[b], sb_t[b], lane);
    if (s + 3 < SHOTS)
      stage32(gout, gtgt, base + (size_t)(s + 3) * 32, lane, sb_o[b], sb_t[b]);
  }

  // lanes 32-63 hold 0; full 64-lane reduce -> one partial per wave/block
  #pragma unroll
  for (int off = 32; off > 0; off >>= 1) acc += __shfl_down(acc, off, 64);
  if (lane == 0) ws[blockIdx.x] = acc;
}

__global__ __launch_bounds__(256) void loc_loss_finalize(
    const float* __restrict__ ws, float* __restrict__ out) {
  __shared__ float s_wave[4];
  const int tid = threadIdx.x;
  const float4* w4 = (const float4*)ws;  // 4096 partials = 1024 float4
  float acc = 0.f;
  #pragma unroll
  for (int i = 0; i < 4; ++i) {
    float4 v = w4[tid + 256 * i];
    acc += (v.x + v.y) + (v.z + v.w);
  }
  #pragma unroll
  for (int off = 32; off > 0; off >>= 1) acc += __shfl_down(acc, off, 64);
  if ((tid & 63) == 0) s_wave[tid >> 6] = acc;
  __syncthreads();
  if (tid == 0) {
    out[0] = (s_wave[0] + s_wave[1] + s_wave[2] + s_wave[3]) * INV_BN + 0.5f;
  }
}

extern "C" void kernel_launch(void* const* d_in, const int* in_sizes, int n_in,
                              void* d_out, int out_size, void* d_ws, size_t ws_size,
                              hipStream_t stream) {
  const float* gout = (const float*)d_in[0];  // (B,3,7)
  const float* gtgt = (const float*)d_in[1];  // (B,3,5)
  float* ws = (float*)d_ws;                   // 4096 floats = 16 KB
  float* out = (float*)d_out;

  loc_loss_kernel<<<NBLK, 64, 0, stream>>>(gout, gtgt, ws);
  loc_loss_finalize<<<1, 256, 0, stream>>>(ws, out);
}